// Round 1
// baseline (957.421 us; speedup 1.0000x reference)
//
#include <hip/hip_runtime.h>
#include <cstdint>
#include <cstddef>

#define DEV __device__ __forceinline__

typedef unsigned short u16;
typedef __attribute__((ext_vector_type(8))) short s16x8;   // 8 x bf16 (raw bits)
typedef __attribute__((ext_vector_type(4))) float f32x4;

typedef unsigned int u32_as1 __attribute__((address_space(1)));
typedef unsigned int u32_as3 __attribute__((address_space(3)));

DEV u16 f2bf(float f){
  unsigned u = __float_as_uint(f);
  u += 0x7fffu + ((u >> 16) & 1u);   // RNE
  return (u16)(u >> 16);
}

DEV void gload16(const void* g, void* l){
  // async global->LDS, 16B per lane; LDS dest = wave-uniform base + lane*16
  __builtin_amdgcn_global_load_lds((const u32_as1*)g, (u32_as3*)l, 16, 0, 0);
}

// ---------- weight transpose+convert: W[K][N] f32 -> Wt[N][K] bf16 ----------
__global__ __launch_bounds__(256) void wconv_kernel(const float* __restrict__ W,
                                                    u16* __restrict__ Wt, int K, int N){
  __shared__ float tl[32][33];
  int tx = threadIdx.x & 31, ty = threadIdx.x >> 5;
  int k0 = blockIdx.x * 32, n0 = blockIdx.y * 32;
  #pragma unroll
  for (int p=0;p<4;p++)
    tl[ty+8*p][tx] = W[(size_t)(k0+ty+8*p)*N + (n0+tx)];
  __syncthreads();
  #pragma unroll
  for (int p=0;p<4;p++){
    int n = ty+8*p;
    Wt[(size_t)(n0+n)*K + (k0+tx)] = f2bf(tl[tx][n]);
  }
}

// ---------- layernorm: in f32 [rows][768] -> bf16 out ----------
__global__ __launch_bounds__(256) void ln_kernel(const float* __restrict__ x,
                                                 const float* __restrict__ g,
                                                 const float* __restrict__ bta,
                                                 u16* __restrict__ out){
  int row = blockIdx.x, t = threadIdx.x;
  const float* xr = x + (size_t)row*768;
  float v0 = xr[t], v1 = xr[t+256], v2 = xr[t+512];
  float s = v0+v1+v2, s2 = v0*v0+v1*v1+v2*v2;
  #pragma unroll
  for (int m=1;m<64;m<<=1){ s += __shfl_xor(s,m); s2 += __shfl_xor(s2,m); }
  __shared__ float ls[4], ls2[4];
  int w = t>>6;
  if ((t&63)==0){ ls[w]=s; ls2[w]=s2; }
  __syncthreads();
  s = ls[0]+ls[1]+ls[2]+ls[3]; s2 = ls2[0]+ls2[1]+ls2[2]+ls2[3];
  float mu = s*(1.0f/768.0f);
  float rstd = rsqrtf(s2*(1.0f/768.0f) - mu*mu + 1e-5f);
  u16* orow = out + (size_t)row*768;
  orow[t]     = f2bf((v0-mu)*rstd*g[t]     + bta[t]);
  orow[t+256] = f2bf((v1-mu)*rstd*g[t+256] + bta[t+256]);
  orow[t+512] = f2bf((v2-mu)*rstd*g[t+512] + bta[t+512]);
}

// ---------- GEMM: C[M][N] = A[M][K](bf16) * Wt[N][K](bf16)^T + bias (+res)(+gelu) ----------
// 128x128 tile, BK=32, 4 waves (2x2), each wave 64x64 = 4x4 MFMA 16x16x32 frags.
template<bool GELU, bool RES, bool OUTBF16>
__global__ __launch_bounds__(256) void gemm_kernel(
    const u16* __restrict__ A, const u16* __restrict__ Bt0, size_t btStride,
    const float* __restrict__ bias0, const float* __restrict__ bias1, const float* __restrict__ bias2,
    const float* __restrict__ res, void* __restrict__ out0, size_t outStride,
    int M, int N, int K)
{
  __shared__ u16 As[128*32];
  __shared__ u16 Bs[128*32];
  const int t = threadIdx.x, lane = t & 63, w = t >> 6;
  const int lj = lane & 15, g = lane >> 4;
  const int wm = w >> 1, wn = w & 1;
  const int z = blockIdx.z;
  const u16* Bt = Bt0 + (size_t)z * btStride;
  const float* bias = (z==0) ? bias0 : (z==1 ? bias1 : bias2);
  const u16* Arow = A  + (size_t)blockIdx.x * 128 * K;
  const u16* Brow = Bt + (size_t)blockIdx.y * 128 * K;

  f32x4 acc[4][4];
  #pragma unroll
  for (int a=0;a<4;a++)
    #pragma unroll
    for (int b=0;b<4;b++){ f32x4 zz = {0.f,0.f,0.f,0.f}; acc[a][b] = zz; }

  for (int kk=0; kk<K; kk+=32){
    #pragma unroll
    for (int s=0;s<2;s++){
      int c = w*128 + s*64 + lane;      // 16B chunk id, 0..511
      int row = c>>2, cc = c&3;
      gload16(Arow + (size_t)row*K + kk + cc*8, (void*)(As + (size_t)(w*128+s*64)*8));
      gload16(Brow + (size_t)row*K + kk + cc*8, (void*)(Bs + (size_t)(w*128+s*64)*8));
    }
    __syncthreads();                    // drains vmcnt: DMA writes visible
    s16x8 af[4], bfr[4];
    #pragma unroll
    for (int mt=0;mt<4;mt++) af[mt]  = *(const s16x8*)&As[(wm*64+mt*16+lj)*32 + g*8];
    #pragma unroll
    for (int nt=0;nt<4;nt++) bfr[nt] = *(const s16x8*)&Bs[(wn*64+nt*16+lj)*32 + g*8];
    #pragma unroll
    for (int mt=0;mt<4;mt++)
      #pragma unroll
      for (int nt=0;nt<4;nt++)
        acc[mt][nt] = __builtin_amdgcn_mfma_f32_16x16x32_bf16(af[mt], bfr[nt], acc[mt][nt], 0,0,0);
    __syncthreads();                    // readers done before next stage
  }

  const size_t gr0 = (size_t)blockIdx.x*128 + wm*64;
  const int gc0 = blockIdx.y*128 + wn*64;
  float* outF = (float*)out0; u16* outB = (u16*)out0;
  if (OUTBF16) outB += (size_t)z*outStride; else outF += (size_t)z*outStride;
  #pragma unroll
  for (int mt=0;mt<4;mt++)
    #pragma unroll
    for (int nt=0;nt<4;nt++){
      int gc = gc0 + nt*16 + lj;
      float bv = bias[gc];
      #pragma unroll
      for (int r=0;r<4;r++){
        size_t gr = gr0 + mt*16 + g*4 + r;     // C/D: col=lane&15, row=4*(lane>>4)+r
        float val = acc[mt][nt][r] + bv;
        if (RES)  val += res[gr*(size_t)N + gc];
        if (GELU) val = 0.5f*val*(1.0f + erff(val*0.70710678118f));
        if (OUTBF16) outB[gr*(size_t)N + gc] = f2bf(val);
        else         outF[gr*(size_t)N + gc] = val;
      }
    }
}

// ---------- attention: per (q-window, head, batch) block; per-key-window softmax ----------
// grid (NW=16, H=12, B=2), 256 threads (4 waves). Q in regs; K/Vt/P in LDS (96KB), XOR-swizzled.
__global__ __launch_bounds__(256,1) void attn_kernel(
    const u16* __restrict__ qb, const u16* __restrict__ kb,
    const u16* __restrict__ vb, u16* __restrict__ ctx)
{
  __shared__ u16 Ks[256*64];       // [krow][d]  row=128B, chunk^=(row&7)
  __shared__ u16 Vts[64*256];      // [d][k]     row=512B, chunk^=(row&31)
  __shared__ u16 Ps[4][16*256];    // per-wave P [q][k], chunk^=row
  const int t = threadIdx.x, lane = t & 63, w = t >> 6;
  const int lj = lane & 15, g = lane >> 4;
  const int iw = blockIdx.x, h = blockIdx.y, b = blockIdx.z;
  const size_t seqbase = (size_t)b * 4096;
  const int hoff = h * 64;

  // Q fragments in registers: qa[pass][kstep], rows w*64+p*16+lj, cols 32*ks+8g..+7
  s16x8 qa[4][2];
  #pragma unroll
  for (int p=0;p<4;p++){
    int qrow = w*64 + p*16 + lj;
    const u16* qp = qb + (seqbase + iw*256 + qrow)*768 + hoff;
    #pragma unroll
    for (int ks=0;ks<2;ks++)
      qa[p][ks] = *(const s16x8*)(qp + ks*32 + g*8);
  }

  f32x4 cacc[4][4];
  #pragma unroll
  for (int p=0;p<4;p++)
    #pragma unroll
    for (int d=0;d<4;d++){ f32x4 zz = {0.f,0.f,0.f,0.f}; cacc[p][d] = zz; }

  for (int jw=0; jw<=iw; jw++){
    // stage K [256][64] swizzled, vectorized
    #pragma unroll
    for (int cc=0;cc<8;cc++){
      int c = cc*256 + t;                  // 2048 chunks of 16B
      int row = c>>3, lch = c&7;
      s16x8 kv = *(const s16x8*)(kb + (seqbase + jw*256 + row)*768 + hoff + lch*8);
      *(s16x8*)&Ks[ row*64 + ((lch ^ (row&7))<<3) ] = kv;
    }
    // stage V transposed -> Vts[d][k], swizzled scalar writes
    #pragma unroll
    for (int cc=0;cc<8;cc++){
      int c = cc*256 + t;
      int row = c>>3, dc = (c&7)*8;        // row = k index, dc = d base
      s16x8 vv = *(const s16x8*)(vb + (seqbase + jw*256 + row)*768 + hoff + dc);
      #pragma unroll
      for (int e=0;e<8;e++){
        int d = dc + e;
        Vts[ d*256 + (((row>>3) ^ (d&31))<<3) + (row&7) ] = ((const u16*)&vv)[e];
      }
    }
    __syncthreads();

    #pragma unroll
    for (int p=0;p<4;p++){
      // S = Q K^T for 16 q-rows x 256 k
      f32x4 sacc[16];
      #pragma unroll
      for (int kt=0;kt<16;kt++){ f32x4 zz = {0.f,0.f,0.f,0.f}; sacc[kt] = zz; }
      #pragma unroll
      for (int kt=0;kt<16;kt++){
        int krow = kt*16 + lj;
        #pragma unroll
        for (int ks=0;ks<2;ks++){
          s16x8 kf = *(const s16x8*)&Ks[ krow*64 + (((4*ks+g) ^ (krow&7))<<3) ];
          sacc[kt] = __builtin_amdgcn_mfma_f32_16x16x32_bf16(qa[p][ks], kf, sacc[kt], 0,0,0);
        }
      }
      // row softmax over 256 k (in-lane over kt, cross-lane over 16-lane group)
      float mr[4], sm[4], rs[4];
      #pragma unroll
      for (int r=0;r<4;r++) mr[r] = sacc[0][r];
      #pragma unroll
      for (int kt=1;kt<16;kt++)
        #pragma unroll
        for (int r=0;r<4;r++) mr[r] = fmaxf(mr[r], sacc[kt][r]);
      #pragma unroll
      for (int msk=1; msk<16; msk<<=1)
        #pragma unroll
        for (int r=0;r<4;r++) mr[r] = fmaxf(mr[r], __shfl_xor(mr[r], msk));
      #pragma unroll
      for (int r=0;r<4;r++) sm[r] = 0.f;
      #pragma unroll
      for (int kt=0;kt<16;kt++)
        #pragma unroll
        for (int r=0;r<4;r++){
          float pv = __expf((sacc[kt][r]-mr[r])*0.125f);
          sacc[kt][r] = pv; sm[r] += pv;
        }
      #pragma unroll
      for (int msk=1; msk<16; msk<<=1)
        #pragma unroll
        for (int r=0;r<4;r++) sm[r] += __shfl_xor(sm[r], msk);
      #pragma unroll
      for (int r=0;r<4;r++) rs[r] = 1.0f / sm[r];
      // write P (C/D layout -> [q][k] in LDS, swizzled)
      #pragma unroll
      for (int kt=0;kt<16;kt++){
        int col = kt*16 + lj, ch = col>>3;
        #pragma unroll
        for (int r=0;r<4;r++){
          int row = g*4 + r;
          Ps[w][ row*256 + ((ch ^ row)<<3) + (col&7) ] = f2bf(sacc[kt][r]*rs[r]);
        }
      }
      // PV: ctx[16 q][64 d] += P[16][256] * V[256][64]
      #pragma unroll
      for (int ks=0;ks<8;ks++){
        s16x8 pa = *(const s16x8*)&Ps[w][ lj*256 + (((4*ks+g) ^ lj)<<3) ];
        #pragma unroll
        for (int dt=0;dt<4;dt++){
          int vrow = dt*16 + lj;
          s16x8 vf = *(const s16x8*)&Vts[ vrow*256 + (((4*ks+g) ^ (vrow&31))<<3) ];
          cacc[p][dt] = __builtin_amdgcn_mfma_f32_16x16x32_bf16(pa, vf, cacc[p][dt], 0,0,0);
        }
      }
    }
    __syncthreads();
  }

  #pragma unroll
  for (int p=0;p<4;p++)
    #pragma unroll
    for (int dt=0;dt<4;dt++)
      #pragma unroll
      for (int r=0;r<4;r++){
        int qrow = w*64 + p*16 + g*4 + r;
        ctx[ (seqbase + iw*256 + qrow)*768 + hoff + dt*16 + lj ] = f2bf(cacc[p][dt][r]);
      }
}

extern "C" void kernel_launch(void* const* d_in, const int* in_sizes, int n_in,
                              void* d_out, int out_size, void* d_ws, size_t ws_size,
                              hipStream_t stream)
{
  const float* x    = (const float*)d_in[0];
  const float* Wq   = (const float*)d_in[1];
  const float* bq   = (const float*)d_in[2];
  const float* Wk   = (const float*)d_in[3];
  const float* bk   = (const float*)d_in[4];
  const float* Wv   = (const float*)d_in[5];
  const float* bv   = (const float*)d_in[6];
  const float* Wo   = (const float*)d_in[7];
  const float* bo   = (const float*)d_in[8];
  const float* ln1g = (const float*)d_in[9];
  const float* ln1b = (const float*)d_in[10];
  const float* W1   = (const float*)d_in[11];
  const float* b1   = (const float*)d_in[12];
  const float* W2   = (const float*)d_in[13];
  const float* b2   = (const float*)d_in[14];
  const float* ln2g = (const float*)d_in[15];
  const float* ln2b = (const float*)d_in[16];

  char* ws = (char*)d_ws;
  constexpr size_t SZ_W768  = (size_t)768*768*2;
  constexpr size_t SZ_W3072 = (size_t)768*3072*2;
  constexpr size_t SZ_HB    = (size_t)8192*768*2;
  u16* wtq = (u16*)(ws);
  u16* wtk = (u16*)(ws + SZ_W768);
  u16* wtv = (u16*)(ws + 2*SZ_W768);
  u16* wto = (u16*)(ws + 3*SZ_W768);
  u16* wt1 = (u16*)(ws + 4*SZ_W768);
  u16* wt2 = (u16*)(ws + 4*SZ_W768 + SZ_W3072);
  char* p0 = ws + 4*SZ_W768 + 2*SZ_W3072;
  u16*   hbuf = (u16*)p0;
  u16*   qbuf = (u16*)(p0 + SZ_HB);
  u16*   kbuf = (u16*)(p0 + 2*SZ_HB);
  u16*   vbuf = (u16*)(p0 + 3*SZ_HB);
  u16*   cbuf = (u16*)(p0 + 4*SZ_HB);
  float* x1   = (float*)(p0 + 5*SZ_HB);
  u16*   ffa  = qbuf;                    // reuse q/k/v/ctx region (exactly 8192*3072*2 bytes)
  float* outp = (float*)d_out;

  // weight transpose + f32->bf16
  wconv_kernel<<<dim3(24,24), 256, 0, stream>>>(Wq, wtq, 768, 768);
  wconv_kernel<<<dim3(24,24), 256, 0, stream>>>(Wk, wtk, 768, 768);
  wconv_kernel<<<dim3(24,24), 256, 0, stream>>>(Wv, wtv, 768, 768);
  wconv_kernel<<<dim3(24,24), 256, 0, stream>>>(Wo, wto, 768, 768);
  wconv_kernel<<<dim3(24,96), 256, 0, stream>>>(W1, wt1, 768, 3072);
  wconv_kernel<<<dim3(96,24), 256, 0, stream>>>(W2, wt2, 3072, 768);

  // LN1
  ln_kernel<<<8192, 256, 0, stream>>>(x, ln1g, ln1b, hbuf);
  // QKV (z-fused)
  gemm_kernel<false,false,true><<<dim3(64,6,3), 256, 0, stream>>>(
      hbuf, wtq, (size_t)768*768, bq, bk, bv, nullptr, qbuf, (size_t)8192*768, 8192, 768, 768);
  // attention
  attn_kernel<<<dim3(16,12,2), 256, 0, stream>>>(qbuf, kbuf, vbuf, cbuf);
  // Wo + residual(x) -> x1 (f32)
  gemm_kernel<false,true,false><<<dim3(64,6,1), 256, 0, stream>>>(
      cbuf, wto, 0, bo, bo, bo, x, x1, 0, 8192, 768, 768);
  // LN2 -> hbuf (bf16)
  ln_kernel<<<8192, 256, 0, stream>>>(x1, ln2g, ln2b, hbuf);
  // FF1 + gelu -> ffa (bf16)
  gemm_kernel<true,false,true><<<dim3(64,24,1), 256, 0, stream>>>(
      hbuf, wt1, 0, b1, b1, b1, nullptr, ffa, 0, 8192, 3072, 768);
  // FF2 + residual(x1) -> out (f32)
  gemm_kernel<false,true,false><<<dim3(64,6,1), 256, 0, stream>>>(
      ffa, wt2, 0, b2, b2, b2, x1, outp, 0, 8192, 768, 3072);
}

// Round 2
// 676.352 us; speedup vs baseline: 1.4156x; 1.4156x over previous
//
#include <hip/hip_runtime.h>
#include <cstdint>
#include <cstddef>

#define DEV __device__ __forceinline__

typedef unsigned short u16;
typedef __attribute__((ext_vector_type(8))) short s16x8;   // 8 x bf16 (raw bits)
typedef __attribute__((ext_vector_type(4))) float f32x4;

typedef unsigned int u32_as1 __attribute__((address_space(1)));
typedef unsigned int u32_as3 __attribute__((address_space(3)));

DEV u16 f2bf(float f){
  unsigned u = __float_as_uint(f);
  u += 0x7fffu + ((u >> 16) & 1u);   // RNE
  return (u16)(u >> 16);
}

DEV void gload16(const void* g, void* l){
  // async global->LDS, 16B per lane; LDS dest = wave-uniform base + lane*16
  __builtin_amdgcn_global_load_lds((const u32_as1*)g, (u32_as3*)l, 16, 0, 0);
}

// ---------- weight transpose+convert: W[K][N] f32 -> Wt[N][K] bf16 ----------
__global__ __launch_bounds__(256) void wconv_kernel(const float* __restrict__ W,
                                                    u16* __restrict__ Wt, int K, int N){
  __shared__ float tl[32][33];
  int tx = threadIdx.x & 31, ty = threadIdx.x >> 5;
  int k0 = blockIdx.x * 32, n0 = blockIdx.y * 32;
  #pragma unroll
  for (int p=0;p<4;p++)
    tl[ty+8*p][tx] = W[(size_t)(k0+ty+8*p)*N + (n0+tx)];
  __syncthreads();
  #pragma unroll
  for (int p=0;p<4;p++){
    int n = ty+8*p;
    Wt[(size_t)(n0+n)*K + (k0+tx)] = f2bf(tl[tx][n]);
  }
}

// ---------- layernorm: in f32 [rows][768] -> bf16 out ----------
__global__ __launch_bounds__(256) void ln_kernel(const float* __restrict__ x,
                                                 const float* __restrict__ g,
                                                 const float* __restrict__ bta,
                                                 u16* __restrict__ out){
  int row = blockIdx.x, t = threadIdx.x;
  const float* xr = x + (size_t)row*768;
  float v0 = xr[t], v1 = xr[t+256], v2 = xr[t+512];
  float s = v0+v1+v2, s2 = v0*v0+v1*v1+v2*v2;
  #pragma unroll
  for (int m=1;m<64;m<<=1){ s += __shfl_xor(s,m); s2 += __shfl_xor(s2,m); }
  __shared__ float ls[4], ls2[4];
  int w = t>>6;
  if ((t&63)==0){ ls[w]=s; ls2[w]=s2; }
  __syncthreads();
  s = ls[0]+ls[1]+ls[2]+ls[3]; s2 = ls2[0]+ls2[1]+ls2[2]+ls2[3];
  float mu = s*(1.0f/768.0f);
  float rstd = rsqrtf(s2*(1.0f/768.0f) - mu*mu + 1e-5f);
  u16* orow = out + (size_t)row*768;
  orow[t]     = f2bf((v0-mu)*rstd*g[t]     + bta[t]);
  orow[t+256] = f2bf((v1-mu)*rstd*g[t+256] + bta[t+256]);
  orow[t+512] = f2bf((v2-mu)*rstd*g[t+512] + bta[t+512]);
}

// ---------- GEMM: C[M][N] = A[M][K](bf16) * Wt[N][K](bf16)^T + bias (+res)(+gelu) ----------
// 128x128 tile, BK=32, 4 waves (2x2), each wave 64x64 = 4x4 MFMA 16x16x32 frags.
template<bool GELU, bool RES, bool OUTBF16>
__global__ __launch_bounds__(256) void gemm_kernel(
    const u16* __restrict__ A, const u16* __restrict__ Bt0, size_t btStride,
    const float* __restrict__ bias0, const float* __restrict__ bias1, const float* __restrict__ bias2,
    const float* __restrict__ res, void* __restrict__ out0, size_t outStride,
    int M, int N, int K)
{
  __shared__ u16 As[128*32];
  __shared__ u16 Bs[128*32];
  const int t = threadIdx.x, lane = t & 63, w = t >> 6;
  const int lj = lane & 15, g = lane >> 4;
  const int wm = w >> 1, wn = w & 1;
  const int z = blockIdx.z;
  const u16* Bt = Bt0 + (size_t)z * btStride;
  const float* bias = (z==0) ? bias0 : (z==1 ? bias1 : bias2);
  const u16* Arow = A  + (size_t)blockIdx.x * 128 * K;
  const u16* Brow = Bt + (size_t)blockIdx.y * 128 * K;

  f32x4 acc[4][4];
  #pragma unroll
  for (int a=0;a<4;a++)
    #pragma unroll
    for (int b=0;b<4;b++){ f32x4 zz = {0.f,0.f,0.f,0.f}; acc[a][b] = zz; }

  for (int kk=0; kk<K; kk+=32){
    #pragma unroll
    for (int s=0;s<2;s++){
      int c = w*128 + s*64 + lane;      // 16B chunk id, 0..511
      int row = c>>2, cc = c&3;
      gload16(Arow + (size_t)row*K + kk + cc*8, (void*)(As + (size_t)(w*128+s*64)*8));
      gload16(Brow + (size_t)row*K + kk + cc*8, (void*)(Bs + (size_t)(w*128+s*64)*8));
    }
    __syncthreads();                    // drains vmcnt: DMA writes visible
    s16x8 af[4], bfr[4];
    #pragma unroll
    for (int mt=0;mt<4;mt++) af[mt]  = *(const s16x8*)&As[(wm*64+mt*16+lj)*32 + g*8];
    #pragma unroll
    for (int nt=0;nt<4;nt++) bfr[nt] = *(const s16x8*)&Bs[(wn*64+nt*16+lj)*32 + g*8];
    #pragma unroll
    for (int mt=0;mt<4;mt++)
      #pragma unroll
      for (int nt=0;nt<4;nt++)
        acc[mt][nt] = __builtin_amdgcn_mfma_f32_16x16x32_bf16(af[mt], bfr[nt], acc[mt][nt], 0,0,0);
    __syncthreads();                    // readers done before next stage
  }

  const size_t gr0 = (size_t)blockIdx.x*128 + wm*64;
  const int gc0 = blockIdx.y*128 + wn*64;
  float* outF = (float*)out0; u16* outB = (u16*)out0;
  if (OUTBF16) outB += (size_t)z*outStride; else outF += (size_t)z*outStride;
  #pragma unroll
  for (int mt=0;mt<4;mt++)
    #pragma unroll
    for (int nt=0;nt<4;nt++){
      int gc = gc0 + nt*16 + lj;
      float bv = bias[gc];
      #pragma unroll
      for (int r=0;r<4;r++){
        size_t gr = gr0 + mt*16 + g*4 + r;     // C/D: col=lane&15, row=4*(lane>>4)+r
        float val = acc[mt][nt][r] + bv;
        if (RES)  val += res[gr*(size_t)N + gc];
        if (GELU) val = 0.5f*val*(1.0f + erff(val*0.70710678118f));
        if (OUTBF16) outB[gr*(size_t)N + gc] = f2bf(val);
        else         outF[gr*(size_t)N + gc] = val;
      }
    }
}

// ---------- attention v2 ----------
// Block = (b, h, iw, q-half): 128 q-rows, 4 waves x 2 passes of 16 q-rows.
// Grid x ordered descending iw (LPT). LDS: K 32K (gload_lds, src-swizzled) +
// Vt 32K (scalar transpose store, bank-spread swizzle) + per-wave P slab 16x40.
__global__ __launch_bounds__(256,2) void attn_kernel(
    const u16* __restrict__ qb, const u16* __restrict__ kb,
    const u16* __restrict__ vb, u16* __restrict__ ctx)
{
  __shared__ u16 Ks[256*64];       // [krow][chunk v]: holds K[row][v^(row&7)]
  __shared__ u16 Vts[64*256];      // [d][chunk p][8k]: p = kb ^ (d&31) ^ ((d>>3)&3)
  __shared__ u16 Ps[4][16*40];     // per-wave P slab [16 q][40 u16 (32 k + pad)]
  const int t = threadIdx.x, lane = t & 63, w = t >> 6;
  const int lj = lane & 15, g = lane >> 4;
  const int bx = blockIdx.x;
  const int iw = 15 - (bx >> 1), qh = bx & 1;
  const int h = blockIdx.y, b = blockIdx.z;
  const size_t seqbase = (size_t)b * 4096;
  const int hoff = h * 64;
  const int qbase = iw*256 + qh*128;

  // Q fragments for both passes (rows qbase + w*32 + p*16 + lj)
  s16x8 qa[2][2];
  #pragma unroll
  for (int p=0;p<2;p++){
    int qrow = qbase + w*32 + p*16 + lj;
    const u16* qp = qb + (seqbase + qrow)*768 + hoff;
    #pragma unroll
    for (int ks=0;ks<2;ks++)
      qa[p][ks] = *(const s16x8*)(qp + ks*32 + g*8);
  }

  f32x4 cacc[2][4];
  #pragma unroll
  for (int p=0;p<2;p++)
    #pragma unroll
    for (int d=0;d<4;d++){ f32x4 zz = {0.f,0.f,0.f,0.f}; cacc[p][d] = zz; }

  for (int jw=0; jw<=iw; jw++){
    const u16* kwin = kb + (seqbase + jw*256)*768 + hoff;
    const u16* vwin = vb + (seqbase + jw*256)*768 + hoff;
    // stage K via global_load_lds; swizzle applied on the GLOBAL source address
    #pragma unroll
    for (int cc=0;cc<8;cc++){
      int c = cc*256 + t;                 // 16B chunk id 0..2047
      int row = c>>3, vpos = c&7;
      int lch = vpos ^ (row&7);
      gload16(kwin + (size_t)row*768 + lch*8, (void*)(Ks + (size_t)(cc*256 + w*64)*8));
    }
    // stage V transposed -> Vts[d][k], swizzled scalar writes
    #pragma unroll
    for (int cc=0;cc<8;cc++){
      int c = cc*256 + t;
      int row = c>>3, dc = (c&7)*8;       // row = k index, dc = d base
      s16x8 vv = *(const s16x8*)(vwin + (size_t)row*768 + dc);
      #pragma unroll
      for (int e=0;e<8;e++){
        int d = dc + e;
        int p2 = (row>>3) ^ (d&31) ^ ((d>>3)&3);
        Vts[ d*256 + p2*8 + (row&7) ] = ((const u16*)&vv)[e];
      }
    }
    __syncthreads();

    #pragma unroll
    for (int p=0;p<2;p++){
      // S = Q K^T for 16 q-rows x 256 k
      f32x4 sacc[16];
      #pragma unroll
      for (int kt=0;kt<16;kt++){ f32x4 zz = {0.f,0.f,0.f,0.f}; sacc[kt] = zz; }
      #pragma unroll
      for (int kt=0;kt<16;kt++){
        int krow = kt*16 + lj;
        #pragma unroll
        for (int ks=0;ks<2;ks++){
          s16x8 kf = *(const s16x8*)&Ks[ krow*64 + (((4*ks+g) ^ (krow&7))<<3) ];
          sacc[kt] = __builtin_amdgcn_mfma_f32_16x16x32_bf16(qa[p][ks], kf, sacc[kt], 0,0,0);
        }
      }
      // row softmax over 256 k (in-lane over kt, cross-lane over 16-lane group)
      float mr[4], sm[4], rs[4];
      #pragma unroll
      for (int r=0;r<4;r++) mr[r] = sacc[0][r];
      #pragma unroll
      for (int kt=1;kt<16;kt++)
        #pragma unroll
        for (int r=0;r<4;r++) mr[r] = fmaxf(mr[r], sacc[kt][r]);
      #pragma unroll
      for (int msk=1; msk<16; msk<<=1)
        #pragma unroll
        for (int r=0;r<4;r++) mr[r] = fmaxf(mr[r], __shfl_xor(mr[r], msk));
      #pragma unroll
      for (int r=0;r<4;r++) sm[r] = 0.f;
      #pragma unroll
      for (int kt=0;kt<16;kt++)
        #pragma unroll
        for (int r=0;r<4;r++){
          float pv = __expf((sacc[kt][r]-mr[r])*0.125f);
          sacc[kt][r] = pv; sm[r] += pv;
        }
      #pragma unroll
      for (int msk=1; msk<16; msk<<=1)
        #pragma unroll
        for (int r=0;r<4;r++) sm[r] += __shfl_xor(sm[r], msk);
      #pragma unroll
      for (int r=0;r<4;r++) rs[r] = 1.0f / sm[r];
      // PV streamed through per-wave P slab, 32 k at a time
      #pragma unroll
      for (int ks=0;ks<8;ks++){
        #pragma unroll
        for (int r=0;r<4;r++){
          Ps[w][ (4*g+r)*40 + lj ]      = f2bf(sacc[2*ks  ][r]*rs[r]);
          Ps[w][ (4*g+r)*40 + 16 + lj ] = f2bf(sacc[2*ks+1][r]*rs[r]);
        }
        s16x8 pa = *(const s16x8*)&Ps[w][ lj*40 + g*8 ];  // row=lj, k=8g..8g+7
        #pragma unroll
        for (int dt=0;dt<4;dt++){
          int d = dt*16 + lj;
          s16x8 vf = *(const s16x8*)&Vts[ d*256 + (((4*ks+g) ^ (d&31) ^ ((d>>3)&3))<<3) ];
          cacc[p][dt] = __builtin_amdgcn_mfma_f32_16x16x32_bf16(pa, vf, cacc[p][dt], 0,0,0);
        }
      }
    }
    __syncthreads();
  }

  #pragma unroll
  for (int p=0;p<2;p++)
    #pragma unroll
    for (int dt=0;dt<4;dt++)
      #pragma unroll
      for (int r=0;r<4;r++){
        int qrow = qbase + w*32 + p*16 + g*4 + r;
        ctx[ (seqbase + qrow)*768 + hoff + dt*16 + lj ] = f2bf(cacc[p][dt][r]);
      }
}

extern "C" void kernel_launch(void* const* d_in, const int* in_sizes, int n_in,
                              void* d_out, int out_size, void* d_ws, size_t ws_size,
                              hipStream_t stream)
{
  const float* x    = (const float*)d_in[0];
  const float* Wq   = (const float*)d_in[1];
  const float* bq   = (const float*)d_in[2];
  const float* Wk   = (const float*)d_in[3];
  const float* bk   = (const float*)d_in[4];
  const float* Wv   = (const float*)d_in[5];
  const float* bv   = (const float*)d_in[6];
  const float* Wo   = (const float*)d_in[7];
  const float* bo   = (const float*)d_in[8];
  const float* ln1g = (const float*)d_in[9];
  const float* ln1b = (const float*)d_in[10];
  const float* W1   = (const float*)d_in[11];
  const float* b1   = (const float*)d_in[12];
  const float* W2   = (const float*)d_in[13];
  const float* b2   = (const float*)d_in[14];
  const float* ln2g = (const float*)d_in[15];
  const float* ln2b = (const float*)d_in[16];

  char* ws = (char*)d_ws;
  constexpr size_t SZ_W768  = (size_t)768*768*2;
  constexpr size_t SZ_W3072 = (size_t)768*3072*2;
  constexpr size_t SZ_HB    = (size_t)8192*768*2;
  u16* wtq = (u16*)(ws);
  u16* wtk = (u16*)(ws + SZ_W768);
  u16* wtv = (u16*)(ws + 2*SZ_W768);
  u16* wto = (u16*)(ws + 3*SZ_W768);
  u16* wt1 = (u16*)(ws + 4*SZ_W768);
  u16* wt2 = (u16*)(ws + 4*SZ_W768 + SZ_W3072);
  char* p0 = ws + 4*SZ_W768 + 2*SZ_W3072;
  u16*   hbuf = (u16*)p0;
  u16*   qbuf = (u16*)(p0 + SZ_HB);
  u16*   kbuf = (u16*)(p0 + 2*SZ_HB);
  u16*   vbuf = (u16*)(p0 + 3*SZ_HB);
  u16*   cbuf = (u16*)(p0 + 4*SZ_HB);
  float* x1   = (float*)(p0 + 5*SZ_HB);
  u16*   ffa  = qbuf;                    // reuse q/k/v/ctx region (exactly 8192*3072*2 bytes)
  float* outp = (float*)d_out;

  // weight transpose + f32->bf16
  wconv_kernel<<<dim3(24,24), 256, 0, stream>>>(Wq, wtq, 768, 768);
  wconv_kernel<<<dim3(24,24), 256, 0, stream>>>(Wk, wtk, 768, 768);
  wconv_kernel<<<dim3(24,24), 256, 0, stream>>>(Wv, wtv, 768, 768);
  wconv_kernel<<<dim3(24,24), 256, 0, stream>>>(Wo, wto, 768, 768);
  wconv_kernel<<<dim3(24,96), 256, 0, stream>>>(W1, wt1, 768, 3072);
  wconv_kernel<<<dim3(96,24), 256, 0, stream>>>(W2, wt2, 3072, 768);

  // LN1
  ln_kernel<<<8192, 256, 0, stream>>>(x, ln1g, ln1b, hbuf);
  // QKV (z-fused)
  gemm_kernel<false,false,true><<<dim3(64,6,3), 256, 0, stream>>>(
      hbuf, wtq, (size_t)768*768, bq, bk, bv, nullptr, qbuf, (size_t)8192*768, 8192, 768, 768);
  // attention
  attn_kernel<<<dim3(32,12,2), 256, 0, stream>>>(qbuf, kbuf, vbuf, cbuf);
  // Wo + residual(x) -> x1 (f32)
  gemm_kernel<false,true,false><<<dim3(64,6,1), 256, 0, stream>>>(
      cbuf, wto, 0, bo, bo, bo, x, x1, 0, 8192, 768, 768);
  // LN2 -> hbuf (bf16)
  ln_kernel<<<8192, 256, 0, stream>>>(x1, ln2g, ln2b, hbuf);
  // FF1 + gelu -> ffa (bf16)
  gemm_kernel<true,false,true><<<dim3(64,24,1), 256, 0, stream>>>(
      hbuf, wt1, 0, b1, b1, b1, nullptr, ffa, 0, 8192, 3072, 768);
  // FF2 + residual(x1) -> out (f32)
  gemm_kernel<false,true,false><<<dim3(64,6,1), 256, 0, stream>>>(
      ffa, wt2, 0, b2, b2, b2, x1, outp, 0, 8192, 768, 3072);
}

// Round 3
// 419.941 us; speedup vs baseline: 2.2799x; 1.6106x over previous
//
#include <hip/hip_runtime.h>
#include <cstdint>
#include <cstddef>

#define DEV __device__ __forceinline__

typedef unsigned short u16;
typedef __attribute__((ext_vector_type(8))) short s16x8;   // 8 x bf16 (raw bits)
typedef __attribute__((ext_vector_type(4))) float f32x4;

typedef unsigned int u32_as1 __attribute__((address_space(1)));
typedef unsigned int u32_as3 __attribute__((address_space(3)));

DEV u16 f2bf(float f){
  unsigned u = __float_as_uint(f);
  u += 0x7fffu + ((u >> 16) & 1u);   // RNE
  return (u16)(u >> 16);
}

DEV void gload16(const void* g, void* l){
  // async global->LDS, 16B per lane; LDS dest = wave-uniform base + lane*16
  __builtin_amdgcn_global_load_lds((const u32_as1*)g, (u32_as3*)l, 16, 0, 0);
}

// ---------- weight transpose+convert: W[K][N] f32 -> Wt[N][K] bf16 ----------
__global__ __launch_bounds__(256) void wconv_kernel(const float* __restrict__ W,
                                                    u16* __restrict__ Wt, int K, int N){
  __shared__ float tl[32][33];
  int tx = threadIdx.x & 31, ty = threadIdx.x >> 5;
  int k0 = blockIdx.x * 32, n0 = blockIdx.y * 32;
  #pragma unroll
  for (int p=0;p<4;p++)
    tl[ty+8*p][tx] = W[(size_t)(k0+ty+8*p)*N + (n0+tx)];
  __syncthreads();
  #pragma unroll
  for (int p=0;p<4;p++){
    int n = ty+8*p;
    Wt[(size_t)(n0+n)*K + (k0+tx)] = f2bf(tl[tx][n]);
  }
}

// ---------- V transpose per head: vbuf[8192][768] bf16 -> vtb[24 bh][64 d][4096 k] ----------
__global__ __launch_bounds__(256) void vconv_kernel(const u16* __restrict__ vbuf,
                                                    u16* __restrict__ vtb){
  int t = threadIdx.x;
  int kt = blockIdx.x, bh = blockIdx.y;
  int b = bh / 12, h = bh - b*12;
  int d = t & 63, kg = t >> 6;
  const u16* src = vbuf + ((size_t)(b*4096 + kt*64) * 768) + h*64 + d;
  u16* dst = vtb + ((size_t)bh*64 + d)*4096 + kt*64;
  #pragma unroll
  for (int j=0;j<2;j++){
    int kc = kg*2 + j;
    s16x8 o;
    #pragma unroll
    for (int e=0;e<8;e++)
      ((u16*)&o)[e] = src[(size_t)(kc*8+e)*768];
    *(s16x8*)(dst + kc*8) = o;
  }
}

// ---------- layernorm: in f32 [rows][768] -> bf16 out ----------
__global__ __launch_bounds__(256) void ln_kernel(const float* __restrict__ x,
                                                 const float* __restrict__ g,
                                                 const float* __restrict__ bta,
                                                 u16* __restrict__ out){
  int row = blockIdx.x, t = threadIdx.x;
  const float* xr = x + (size_t)row*768;
  float v0 = xr[t], v1 = xr[t+256], v2 = xr[t+512];
  float s = v0+v1+v2, s2 = v0*v0+v1*v1+v2*v2;
  #pragma unroll
  for (int m=1;m<64;m<<=1){ s += __shfl_xor(s,m); s2 += __shfl_xor(s2,m); }
  __shared__ float ls[4], ls2[4];
  int w = t>>6;
  if ((t&63)==0){ ls[w]=s; ls2[w]=s2; }
  __syncthreads();
  s = ls[0]+ls[1]+ls[2]+ls[3]; s2 = ls2[0]+ls2[1]+ls2[2]+ls2[3];
  float mu = s*(1.0f/768.0f);
  float rstd = rsqrtf(s2*(1.0f/768.0f) - mu*mu + 1e-5f);
  u16* orow = out + (size_t)row*768;
  orow[t]     = f2bf((v0-mu)*rstd*g[t]     + bta[t]);
  orow[t+256] = f2bf((v1-mu)*rstd*g[t+256] + bta[t+256]);
  orow[t+512] = f2bf((v2-mu)*rstd*g[t+512] + bta[t+512]);
}

// ---------- GEMM: C[M][N] = A[M][K](bf16) * Wt[N][K](bf16)^T + bias (+res)(+gelu) ----------
template<bool GELU, bool RES, bool OUTBF16>
__global__ __launch_bounds__(256) void gemm_kernel(
    const u16* __restrict__ A, const u16* __restrict__ Bt0, size_t btStride,
    const float* __restrict__ bias0, const float* __restrict__ bias1, const float* __restrict__ bias2,
    const float* __restrict__ res, void* __restrict__ out0, size_t outStride,
    int M, int N, int K)
{
  __shared__ u16 As[128*32];
  __shared__ u16 Bs[128*32];
  const int t = threadIdx.x, lane = t & 63, w = t >> 6;
  const int lj = lane & 15, g = lane >> 4;
  const int wm = w >> 1, wn = w & 1;
  const int z = blockIdx.z;
  const u16* Bt = Bt0 + (size_t)z * btStride;
  const float* bias = (z==0) ? bias0 : (z==1 ? bias1 : bias2);
  const u16* Arow = A  + (size_t)blockIdx.x * 128 * K;
  const u16* Brow = Bt + (size_t)blockIdx.y * 128 * K;

  f32x4 acc[4][4];
  #pragma unroll
  for (int a=0;a<4;a++)
    #pragma unroll
    for (int b=0;b<4;b++){ f32x4 zz = {0.f,0.f,0.f,0.f}; acc[a][b] = zz; }

  for (int kk=0; kk<K; kk+=32){
    #pragma unroll
    for (int s=0;s<2;s++){
      int c = w*128 + s*64 + lane;      // 16B chunk id, 0..511
      int row = c>>2, cc = c&3;
      gload16(Arow + (size_t)row*K + kk + cc*8, (void*)(As + (size_t)(w*128+s*64)*8));
      gload16(Brow + (size_t)row*K + kk + cc*8, (void*)(Bs + (size_t)(w*128+s*64)*8));
    }
    __syncthreads();
    s16x8 af[4], bfr[4];
    #pragma unroll
    for (int mt=0;mt<4;mt++) af[mt]  = *(const s16x8*)&As[(wm*64+mt*16+lj)*32 + g*8];
    #pragma unroll
    for (int nt=0;nt<4;nt++) bfr[nt] = *(const s16x8*)&Bs[(wn*64+nt*16+lj)*32 + g*8];
    #pragma unroll
    for (int mt=0;mt<4;mt++)
      #pragma unroll
      for (int nt=0;nt<4;nt++)
        acc[mt][nt] = __builtin_amdgcn_mfma_f32_16x16x32_bf16(af[mt], bfr[nt], acc[mt][nt], 0,0,0);
    __syncthreads();
  }

  const size_t gr0 = (size_t)blockIdx.x*128 + wm*64;
  const int gc0 = blockIdx.y*128 + wn*64;
  float* outF = (float*)out0; u16* outB = (u16*)out0;
  if (OUTBF16) outB += (size_t)z*outStride; else outF += (size_t)z*outStride;
  #pragma unroll
  for (int mt=0;mt<4;mt++)
    #pragma unroll
    for (int nt=0;nt<4;nt++){
      int gc = gc0 + nt*16 + lj;
      float bv = bias[gc];
      #pragma unroll
      for (int r=0;r<4;r++){
        size_t gr = gr0 + mt*16 + g*4 + r;
        float val = acc[mt][nt][r] + bv;
        if (RES)  val += res[gr*(size_t)N + gc];
        if (GELU) val = 0.5f*val*(1.0f + erff(val*0.70710678118f));
        if (OUTBF16) outB[gr*(size_t)N + gc] = f2bf(val);
        else         outF[gr*(size_t)N + gc] = val;
      }
    }
}

// ---------- attention v3 ----------
// Block = (b, h, q-quarter of 64 rows, pair pp): phase0 iw=pp, phase1 iw=15-pp
// -> 17 window-units per block, 768 equal blocks, 3 blocks/CU all resident.
// LDS 53KB: K half-window 16KB (staged twice per window), V full 32KB (vtb,
// gload_lds pre-swizzled src), per-wave P slab 5KB. 1 pass of 16 q per wave.
__global__ __launch_bounds__(256,3) void attn_kernel(
    const u16* __restrict__ qb, const u16* __restrict__ kb,
    const u16* __restrict__ vtb, u16* __restrict__ ctx)
{
  __shared__ u16 Ks[128*64];       // [krow 128][8 chunks], chunk^=(krow&7)
  __shared__ u16 Vs[64*256];       // [d 64][32 chunks], chunk^=(d&15)
  __shared__ u16 Ps[4][16*40];     // per-wave P slab [16 q][40]
  const int t = threadIdx.x, lane = t & 63, w = t >> 6;
  const int lj = lane & 15, g = lane >> 4;
  const int bx = blockIdx.x;
  const int pp = bx & 7, qq = (bx >> 3) & 3, bh = bx >> 5;
  const int h = bh % 12, b = bh / 12;
  const size_t seqbase = (size_t)b * 4096;
  const int hoff = h * 64;

  #pragma unroll
  for (int f=0; f<2; f++){
    const int iw = f ? (15 - pp) : pp;
    const int qrow0 = iw*256 + qq*64 + w*16;

    s16x8 qa[2];
    #pragma unroll
    for (int ks=0;ks<2;ks++)
      qa[ks] = *(const s16x8*)(qb + (seqbase + qrow0 + lj)*768 + hoff + ks*32 + g*8);

    f32x4 cacc[4];
    #pragma unroll
    for (int dt=0;dt<4;dt++){ f32x4 zz = {0.f,0.f,0.f,0.f}; cacc[dt] = zz; }

    for (int jw=0; jw<=iw; jw++){
      const u16* kwin = kb + (seqbase + jw*256)*768 + hoff;
      const u16* vtwin = vtb + (size_t)bh*64*4096 + jw*256;
      // A: stage K half 1 + V full
      #pragma unroll
      for (int cc=0;cc<4;cc++){
        int c = cc*256 + w*64 + lane;
        int krow = c>>3, vp = c&7;
        gload16(kwin + (size_t)krow*768 + ((vp ^ (krow&7))<<3),
                (void*)(Ks + (size_t)(cc*256 + w*64)*8));
      }
      #pragma unroll
      for (int cc=0;cc<8;cc++){
        int c = cc*256 + w*64 + lane;
        int d = c>>5, cp = c&31;
        gload16(vtwin + (size_t)d*4096 + ((cp ^ (d&15))<<3),
                (void*)(Vs + (size_t)(cc*256 + w*64)*8));
      }
      __syncthreads();

      f32x4 sacc[16];
      #pragma unroll
      for (int kt=0;kt<16;kt++){ f32x4 zz = {0.f,0.f,0.f,0.f}; sacc[kt] = zz; }
      // B: QK^T on k-half 1
      __builtin_amdgcn_s_setprio(1);
      #pragma unroll
      for (int kt=0;kt<8;kt++){
        int kl = kt*16 + lj;
        #pragma unroll
        for (int ks=0;ks<2;ks++){
          s16x8 kf = *(const s16x8*)&Ks[ (size_t)kl*64 + (((4*ks+g) ^ (kl&7))<<3) ];
          sacc[kt] = __builtin_amdgcn_mfma_f32_16x16x32_bf16(qa[ks], kf, sacc[kt], 0,0,0);
        }
      }
      __builtin_amdgcn_s_setprio(0);
      __syncthreads();
      // C: stage K half 2
      #pragma unroll
      for (int cc=0;cc<4;cc++){
        int c = cc*256 + w*64 + lane;
        int krow = c>>3, vp = c&7;
        gload16(kwin + (size_t)(128+krow)*768 + ((vp ^ (krow&7))<<3),
                (void*)(Ks + (size_t)(cc*256 + w*64)*8));
      }
      __syncthreads();
      // D: QK^T on k-half 2
      __builtin_amdgcn_s_setprio(1);
      #pragma unroll
      for (int kt=8;kt<16;kt++){
        int kl = (kt-8)*16 + lj;
        #pragma unroll
        for (int ks=0;ks<2;ks++){
          s16x8 kf = *(const s16x8*)&Ks[ (size_t)kl*64 + (((4*ks+g) ^ (kl&7))<<3) ];
          sacc[kt] = __builtin_amdgcn_mfma_f32_16x16x32_bf16(qa[ks], kf, sacc[kt], 0,0,0);
        }
      }
      __builtin_amdgcn_s_setprio(0);
      // softmax over 256 k (in-lane kt, cross-lane 16-group)
      float mr[4], sm[4], rs[4];
      #pragma unroll
      for (int r=0;r<4;r++) mr[r] = sacc[0][r];
      #pragma unroll
      for (int kt=1;kt<16;kt++)
        #pragma unroll
        for (int r=0;r<4;r++) mr[r] = fmaxf(mr[r], sacc[kt][r]);
      #pragma unroll
      for (int msk=1; msk<16; msk<<=1)
        #pragma unroll
        for (int r=0;r<4;r++) mr[r] = fmaxf(mr[r], __shfl_xor(mr[r], msk));
      #pragma unroll
      for (int r=0;r<4;r++) sm[r] = 0.f;
      #pragma unroll
      for (int kt=0;kt<16;kt++)
        #pragma unroll
        for (int r=0;r<4;r++){
          float pv = __expf((sacc[kt][r]-mr[r])*0.125f);
          sacc[kt][r] = pv; sm[r] += pv;
        }
      #pragma unroll
      for (int msk=1; msk<16; msk<<=1)
        #pragma unroll
        for (int r=0;r<4;r++) sm[r] += __shfl_xor(sm[r], msk);
      #pragma unroll
      for (int r=0;r<4;r++) rs[r] = 1.0f / sm[r];
      // PV streamed through per-wave P slab, 32 k at a time
      #pragma unroll
      for (int ks=0;ks<8;ks++){
        #pragma unroll
        for (int r=0;r<4;r++){
          Ps[w][ (4*g+r)*40 + lj ]      = f2bf(sacc[2*ks  ][r]*rs[r]);
          Ps[w][ (4*g+r)*40 + 16 + lj ] = f2bf(sacc[2*ks+1][r]*rs[r]);
        }
        s16x8 pa = *(const s16x8*)&Ps[w][ lj*40 + g*8 ];
        __builtin_amdgcn_s_setprio(1);
        #pragma unroll
        for (int dt=0;dt<4;dt++){
          int d = dt*16 + lj;
          s16x8 vf = *(const s16x8*)&Vs[ (size_t)d*256 + (((4*ks+g) ^ (d&15))<<3) ];
          cacc[dt] = __builtin_amdgcn_mfma_f32_16x16x32_bf16(pa, vf, cacc[dt], 0,0,0);
        }
        __builtin_amdgcn_s_setprio(0);
      }
      __syncthreads();
    }

    #pragma unroll
    for (int dt=0;dt<4;dt++)
      #pragma unroll
      for (int r=0;r<4;r++){
        int qrow = qrow0 + g*4 + r;
        ctx[ (seqbase + qrow)*768 + hoff + dt*16 + lj ] = f2bf(cacc[dt][r]);
      }
  }
}

extern "C" void kernel_launch(void* const* d_in, const int* in_sizes, int n_in,
                              void* d_out, int out_size, void* d_ws, size_t ws_size,
                              hipStream_t stream)
{
  const float* x    = (const float*)d_in[0];
  const float* Wq   = (const float*)d_in[1];
  const float* bq   = (const float*)d_in[2];
  const float* Wk   = (const float*)d_in[3];
  const float* bk   = (const float*)d_in[4];
  const float* Wv   = (const float*)d_in[5];
  const float* bv   = (const float*)d_in[6];
  const float* Wo   = (const float*)d_in[7];
  const float* bo   = (const float*)d_in[8];
  const float* ln1g = (const float*)d_in[9];
  const float* ln1b = (const float*)d_in[10];
  const float* W1   = (const float*)d_in[11];
  const float* b1   = (const float*)d_in[12];
  const float* W2   = (const float*)d_in[13];
  const float* b2   = (const float*)d_in[14];
  const float* ln2g = (const float*)d_in[15];
  const float* ln2b = (const float*)d_in[16];

  char* ws = (char*)d_ws;
  constexpr size_t SZ_W768  = (size_t)768*768*2;
  constexpr size_t SZ_W3072 = (size_t)768*3072*2;
  constexpr size_t SZ_HB    = (size_t)8192*768*2;
  u16* wtq = (u16*)(ws);
  u16* wtk = (u16*)(ws + SZ_W768);
  u16* wtv = (u16*)(ws + 2*SZ_W768);
  u16* wto = (u16*)(ws + 3*SZ_W768);
  u16* wt1 = (u16*)(ws + 4*SZ_W768);
  u16* wt2 = (u16*)(ws + 4*SZ_W768 + SZ_W3072);
  char* p0 = ws + 4*SZ_W768 + 2*SZ_W3072;
  u16*   hbuf = (u16*)p0;               // LN out; later aliased as vtbuf, then LN2 out
  u16*   qbuf = (u16*)(p0 + SZ_HB);
  u16*   kbuf = (u16*)(p0 + 2*SZ_HB);
  u16*   vbuf = (u16*)(p0 + 3*SZ_HB);
  u16*   cbuf = (u16*)(p0 + 4*SZ_HB);
  float* x1   = (float*)(p0 + 5*SZ_HB);
  u16*   vtbuf = hbuf;                  // 24*64*4096*2 == 8192*768*2 bytes exactly
  u16*   ffa  = qbuf;                   // reuse q/k/v region for FF activations
  float* outp = (float*)d_out;

  // weight transpose + f32->bf16
  wconv_kernel<<<dim3(24,24), 256, 0, stream>>>(Wq, wtq, 768, 768);
  wconv_kernel<<<dim3(24,24), 256, 0, stream>>>(Wk, wtk, 768, 768);
  wconv_kernel<<<dim3(24,24), 256, 0, stream>>>(Wv, wtv, 768, 768);
  wconv_kernel<<<dim3(24,24), 256, 0, stream>>>(Wo, wto, 768, 768);
  wconv_kernel<<<dim3(24,96), 256, 0, stream>>>(W1, wt1, 768, 3072);
  wconv_kernel<<<dim3(96,24), 256, 0, stream>>>(W2, wt2, 3072, 768);

  // LN1 -> hbuf
  ln_kernel<<<8192, 256, 0, stream>>>(x, ln1g, ln1b, hbuf);
  // QKV (z-fused)
  gemm_kernel<false,false,true><<<dim3(64,6,3), 256, 0, stream>>>(
      hbuf, wtq, (size_t)768*768, bq, bk, bv, nullptr, qbuf, (size_t)8192*768, 8192, 768, 768);
  // V per-head transpose -> vtbuf (aliases hbuf; QKV already consumed hbuf)
  vconv_kernel<<<dim3(64,24), 256, 0, stream>>>(vbuf, vtbuf);
  // attention
  attn_kernel<<<768, 256, 0, stream>>>(qbuf, kbuf, vtbuf, cbuf);
  // Wo + residual(x) -> x1 (f32)
  gemm_kernel<false,true,false><<<dim3(64,6,1), 256, 0, stream>>>(
      cbuf, wto, 0, bo, bo, bo, x, x1, 0, 8192, 768, 768);
  // LN2 -> hbuf (bf16; overwrites vtbuf, attention is done)
  ln_kernel<<<8192, 256, 0, stream>>>(x1, ln2g, ln2b, hbuf);
  // FF1 + gelu -> ffa (bf16)
  gemm_kernel<true,false,true><<<dim3(64,24,1), 256, 0, stream>>>(
      hbuf, wt1, 0, b1, b1, b1, nullptr, ffa, 0, 8192, 3072, 768);
  // FF2 + residual(x1) -> out (f32)
  gemm_kernel<false,true,false><<<dim3(64,6,1), 256, 0, stream>>>(
      ffa, wt2, 0, b2, b2, b2, x1, outp, 0, 8192, 768, 3072);
}

// Round 4
// 368.381 us; speedup vs baseline: 2.5990x; 1.1400x over previous
//
#include <hip/hip_runtime.h>
#include <cstdint>
#include <cstddef>

#define DEV __device__ __forceinline__

typedef unsigned short u16;
typedef unsigned int u32;
typedef __attribute__((ext_vector_type(8))) short s16x8;   // 8 x bf16 (raw bits)
typedef __attribute__((ext_vector_type(4))) float f32x4;

typedef unsigned int u32_as1 __attribute__((address_space(1)));
typedef unsigned int u32_as3 __attribute__((address_space(3)));

DEV u16 f2bf(float f){
  unsigned u = __float_as_uint(f);
  u += 0x7fffu + ((u >> 16) & 1u);   // RNE
  return (u16)(u >> 16);
}

DEV u32 cvtpk_bf16(float lo, float hi){
  u32 r;
  asm("v_cvt_pk_bf16_f32 %0, %1, %2" : "=v"(r) : "v"(lo), "v"(hi));
  return r;
}

DEV void gload16(const void* g, void* l){
  // async global->LDS, 16B per lane; LDS dest = wave-uniform base + lane*16
  __builtin_amdgcn_global_load_lds((const u32_as1*)g, (u32_as3*)l, 16, 0, 0);
}

// ---------- weight transpose+convert: W[K][N] f32 -> Wt[N][K] bf16 ----------
__global__ __launch_bounds__(256) void wconv_kernel(const float* __restrict__ W,
                                                    u16* __restrict__ Wt, int K, int N){
  __shared__ float tl[32][33];
  int tx = threadIdx.x & 31, ty = threadIdx.x >> 5;
  int k0 = blockIdx.x * 32, n0 = blockIdx.y * 32;
  #pragma unroll
  for (int p=0;p<4;p++)
    tl[ty+8*p][tx] = W[(size_t)(k0+ty+8*p)*N + (n0+tx)];
  __syncthreads();
  #pragma unroll
  for (int p=0;p<4;p++){
    int n = ty+8*p;
    Wt[(size_t)(n0+n)*K + (k0+tx)] = f2bf(tl[tx][n]);
  }
}

// ---------- V transpose per head with k-interleave perm ----------
// vbuf[8192][768] bf16 -> vtb[24 bh][64 d][4096 pos]; within each 32-k chunk,
// position p holds k_local = (p>>1) + 16*(p&1)  (pairs (k,k+16) adjacent).
__global__ __launch_bounds__(256) void vconv_kernel(const u16* __restrict__ vbuf,
                                                    u16* __restrict__ vtb){
  int t = threadIdx.x;
  int kt = blockIdx.x, bh = blockIdx.y;
  int b = bh / 12, h = bh - b*12;
  int d = t & 63, kg = t >> 6;
  const u16* src = vbuf + ((size_t)(b*4096 + kt*64) * 768) + h*64 + d;
  u16* dst = vtb + ((size_t)bh*64 + d)*4096 + kt*64;
  #pragma unroll
  for (int j=0;j<2;j++){
    int kc = kg*2 + j;                 // 16B granule 0..7 within the 64-k tile
    s16x8 o;
    #pragma unroll
    for (int e=0;e<8;e++){
      int klocal = (kc>>2)*32 + 4*(kc&3) + (e>>1) + 16*(e&1);
      ((u16*)&o)[e] = src[(size_t)klocal*768];
    }
    *(s16x8*)(dst + kc*8) = o;
  }
}

// ---------- layernorm: in f32 [rows][768] -> bf16 out ----------
__global__ __launch_bounds__(256) void ln_kernel(const float* __restrict__ x,
                                                 const float* __restrict__ g,
                                                 const float* __restrict__ bta,
                                                 u16* __restrict__ out){
  int row = blockIdx.x, t = threadIdx.x;
  const float* xr = x + (size_t)row*768;
  float v0 = xr[t], v1 = xr[t+256], v2 = xr[t+512];
  float s = v0+v1+v2, s2 = v0*v0+v1*v1+v2*v2;
  #pragma unroll
  for (int m=1;m<64;m<<=1){ s += __shfl_xor(s,m); s2 += __shfl_xor(s2,m); }
  __shared__ float ls[4], ls2[4];
  int w = t>>6;
  if ((t&63)==0){ ls[w]=s; ls2[w]=s2; }
  __syncthreads();
  s = ls[0]+ls[1]+ls[2]+ls[3]; s2 = ls2[0]+ls2[1]+ls2[2]+ls2[3];
  float mu = s*(1.0f/768.0f);
  float rstd = rsqrtf(s2*(1.0f/768.0f) - mu*mu + 1e-5f);
  u16* orow = out + (size_t)row*768;
  orow[t]     = f2bf((v0-mu)*rstd*g[t]     + bta[t]);
  orow[t+256] = f2bf((v1-mu)*rstd*g[t+256] + bta[t+256]);
  orow[t+512] = f2bf((v2-mu)*rstd*g[t+512] + bta[t+512]);
}

// ---------- GEMM: C[M][N] = A[M][K](bf16) * Wt[N][K](bf16)^T + bias (+res)(+gelu) ----------
template<bool GELU, bool RES, bool OUTBF16>
__global__ __launch_bounds__(256) void gemm_kernel(
    const u16* __restrict__ A, const u16* __restrict__ Bt0, size_t btStride,
    const float* __restrict__ bias0, const float* __restrict__ bias1, const float* __restrict__ bias2,
    const float* __restrict__ res, void* __restrict__ out0, size_t outStride,
    int M, int N, int K, float qscale)
{
  __shared__ u16 As[128*32];
  __shared__ u16 Bs[128*32];
  const int t = threadIdx.x, lane = t & 63, w = t >> 6;
  const int lj = lane & 15, g = lane >> 4;
  const int wm = w >> 1, wn = w & 1;
  const int z = blockIdx.z;
  const u16* Bt = Bt0 + (size_t)z * btStride;
  const float* bias = (z==0) ? bias0 : (z==1 ? bias1 : bias2);
  const u16* Arow = A  + (size_t)blockIdx.x * 128 * K;
  const u16* Brow = Bt + (size_t)blockIdx.y * 128 * K;

  f32x4 acc[4][4];
  #pragma unroll
  for (int a=0;a<4;a++)
    #pragma unroll
    for (int b=0;b<4;b++){ f32x4 zz = {0.f,0.f,0.f,0.f}; acc[a][b] = zz; }

  for (int kk=0; kk<K; kk+=32){
    #pragma unroll
    for (int s=0;s<2;s++){
      int c = w*128 + s*64 + lane;      // 16B chunk id, 0..511
      int row = c>>2, cc = c&3;
      gload16(Arow + (size_t)row*K + kk + cc*8, (void*)(As + (size_t)(w*128+s*64)*8));
      gload16(Brow + (size_t)row*K + kk + cc*8, (void*)(Bs + (size_t)(w*128+s*64)*8));
    }
    __syncthreads();
    s16x8 af[4], bfr[4];
    #pragma unroll
    for (int mt=0;mt<4;mt++) af[mt]  = *(const s16x8*)&As[(wm*64+mt*16+lj)*32 + g*8];
    #pragma unroll
    for (int nt=0;nt<4;nt++) bfr[nt] = *(const s16x8*)&Bs[(wn*64+nt*16+lj)*32 + g*8];
    #pragma unroll
    for (int mt=0;mt<4;mt++)
      #pragma unroll
      for (int nt=0;nt<4;nt++)
        acc[mt][nt] = __builtin_amdgcn_mfma_f32_16x16x32_bf16(af[mt], bfr[nt], acc[mt][nt], 0,0,0);
    __syncthreads();
  }

  const size_t gr0 = (size_t)blockIdx.x*128 + wm*64;
  const int gc0 = blockIdx.y*128 + wn*64;
  float* outF = (float*)out0; u16* outB = (u16*)out0;
  if (OUTBF16) outB += (size_t)z*outStride; else outF += (size_t)z*outStride;
  #pragma unroll
  for (int mt=0;mt<4;mt++)
    #pragma unroll
    for (int nt=0;nt<4;nt++){
      int gc = gc0 + nt*16 + lj;
      float bv = bias[gc];
      #pragma unroll
      for (int r=0;r<4;r++){
        size_t gr = gr0 + mt*16 + g*4 + r;
        float val = acc[mt][nt][r] + bv;
        if (z==0) val *= qscale;
        if (RES)  val += res[gr*(size_t)N + gc];
        if (GELU) val = 0.5f*val*(1.0f + erff(val*0.70710678118f));
        if (OUTBF16) outB[gr*(size_t)N + gc] = f2bf(val);
        else         outF[gr*(size_t)N + gc] = val;
      }
    }
}

// ---------- attention v4 ----------
// Block = (b, h, q-quarter 64 rows, pair pp): iw=pp then iw=15-pp -> 17 units.
// One 32KB KV buffer: stage K -> QK -> stage V (latency hidden under softmax)
// -> PV. P packed via v_cvt_pk_bf16_f32 into per-wave u32 slab; V stored in
// k-interleaved perm order (matches P packing) so MFMA slots agree.
__global__ __launch_bounds__(256,3) void attn_kernel(
    const u16* __restrict__ qb, const u16* __restrict__ kb,
    const u16* __restrict__ vtb, u16* __restrict__ ctx)
{
  __shared__ u16 KV[256*64];       // K: [krow 256][8 gran, ^=(krow&7)] ; V: [d 64][32 gran, ^=(d&15)]
  __shared__ u32 Ps[4][16*20];     // per-wave P [16 q][16 dwords + 4 pad]
  const int t = threadIdx.x, lane = t & 63, w = t >> 6;
  const int lj = lane & 15, g = lane >> 4;
  const int bx = blockIdx.x;
  const int pp = bx & 7, qq = (bx >> 3) & 3, bh = bx >> 5;
  const int h = bh % 12, b = bh / 12;
  const size_t seqbase = (size_t)b * 4096;
  const int hoff = h * 64;

  #pragma unroll
  for (int f=0; f<2; f++){
    const int iw = f ? (15 - pp) : pp;
    const int qrow0 = iw*256 + qq*64 + w*16;

    s16x8 qa[2];
    #pragma unroll
    for (int ks=0;ks<2;ks++)
      qa[ks] = *(const s16x8*)(qb + (seqbase + qrow0 + lj)*768 + hoff + ks*32 + g*8);

    f32x4 cacc[4];
    #pragma unroll
    for (int dt=0;dt<4;dt++){ f32x4 zz = {0.f,0.f,0.f,0.f}; cacc[dt] = zz; }

    for (int jw=0; jw<=iw; jw++){
      const u16* kwin = kb + (seqbase + jw*256)*768 + hoff;
      const u16* vtwin = vtb + (size_t)bh*64*4096 + jw*256;

      __syncthreads();                       // prev PV reads done before K overwrite
      // stage K full window (2048 granules)
      #pragma unroll
      for (int cc=0;cc<8;cc++){
        int c = cc*256 + t;
        int krow = c>>3, vp = c&7;
        gload16(kwin + (size_t)krow*768 + ((vp ^ (krow&7))<<3),
                (void*)(KV + (size_t)(cc*256 + w*64)*8));
      }
      __syncthreads();                       // K visible

      f32x4 sacc[16];
      #pragma unroll
      for (int kt=0;kt<16;kt++){ f32x4 zz = {0.f,0.f,0.f,0.f}; sacc[kt] = zz; }
      __builtin_amdgcn_s_setprio(1);
      #pragma unroll
      for (int kt=0;kt<16;kt++){
        int kl = kt*16 + lj;
        #pragma unroll
        for (int ks=0;ks<2;ks++){
          s16x8 kf = *(const s16x8*)&KV[ (size_t)kl*64 + (((4*ks+g) ^ (kl&7))<<3) ];
          sacc[kt] = __builtin_amdgcn_mfma_f32_16x16x32_bf16(qa[ks], kf, sacc[kt], 0,0,0);
        }
      }
      __builtin_amdgcn_s_setprio(0);
      __syncthreads();                       // QK reads of KV done

      // stage V (perm layout) -- latency hides under softmax below
      #pragma unroll
      for (int cc=0;cc<8;cc++){
        int c = cc*256 + t;
        int d = c>>5, cp = c&31;
        gload16(vtwin + (size_t)d*4096 + ((cp ^ (d&15))<<3),
                (void*)(KV + (size_t)(cc*256 + w*64)*8));
      }

      // softmax over 256 k (scores pre-scaled by 0.125 via Q epilogue)
      float mr[4], sm[4], rs[4];
      #pragma unroll
      for (int r=0;r<4;r++) mr[r] = sacc[0][r];
      #pragma unroll
      for (int kt=1;kt<16;kt++)
        #pragma unroll
        for (int r=0;r<4;r++) mr[r] = fmaxf(mr[r], sacc[kt][r]);
      #pragma unroll
      for (int msk=1; msk<16; msk<<=1)
        #pragma unroll
        for (int r=0;r<4;r++) mr[r] = fmaxf(mr[r], __shfl_xor(mr[r], msk));
      #pragma unroll
      for (int r=0;r<4;r++) sm[r] = 0.f;
      #pragma unroll
      for (int kt=0;kt<16;kt++)
        #pragma unroll
        for (int r=0;r<4;r++){
          float pv = __expf(sacc[kt][r]-mr[r]);
          sacc[kt][r] = pv; sm[r] += pv;
        }
      #pragma unroll
      for (int msk=1; msk<16; msk<<=1)
        #pragma unroll
        for (int r=0;r<4;r++) sm[r] += __shfl_xor(sm[r], msk);
      #pragma unroll
      for (int r=0;r<4;r++) rs[r] = 1.0f / sm[r];
      #pragma unroll
      for (int kt=0;kt<16;kt++)
        #pragma unroll
        for (int r=0;r<4;r++) sacc[kt][r] *= rs[r];

      __syncthreads();                       // V visible (drains stage-V vmcnt)

      // PV streamed: pack 32-k chunk (pairs (k,k+16) -> one dword), read A-frag, 4 MFMA
      #pragma unroll
      for (int ks=0;ks<8;ks++){
        #pragma unroll
        for (int r=0;r<4;r++)
          Ps[w][ (4*g+r)*20 + lj ] = cvtpk_bf16(sacc[2*ks][r], sacc[2*ks+1][r]);
        s16x8 pa = *(const s16x8*)&Ps[w][ lj*20 + g*4 ];
        __builtin_amdgcn_s_setprio(1);
        #pragma unroll
        for (int dt=0;dt<4;dt++){
          int d = dt*16 + lj;
          s16x8 vf = *(const s16x8*)&KV[ (size_t)d*256 + (((4*ks+g) ^ (d&15))<<3) ];
          cacc[dt] = __builtin_amdgcn_mfma_f32_16x16x32_bf16(pa, vf, cacc[dt], 0,0,0);
        }
        __builtin_amdgcn_s_setprio(0);
      }
    }

    #pragma unroll
    for (int dt=0;dt<4;dt++)
      #pragma unroll
      for (int r=0;r<4;r++){
        int qrow = qrow0 + g*4 + r;
        ctx[ (seqbase + qrow)*768 + hoff + dt*16 + lj ] = f2bf(cacc[dt][r]);
      }
  }
}

extern "C" void kernel_launch(void* const* d_in, const int* in_sizes, int n_in,
                              void* d_out, int out_size, void* d_ws, size_t ws_size,
                              hipStream_t stream)
{
  const float* x    = (const float*)d_in[0];
  const float* Wq   = (const float*)d_in[1];
  const float* bq   = (const float*)d_in[2];
  const float* Wk   = (const float*)d_in[3];
  const float* bk   = (const float*)d_in[4];
  const float* Wv   = (const float*)d_in[5];
  const float* bv   = (const float*)d_in[6];
  const float* Wo   = (const float*)d_in[7];
  const float* bo   = (const float*)d_in[8];
  const float* ln1g = (const float*)d_in[9];
  const float* ln1b = (const float*)d_in[10];
  const float* W1   = (const float*)d_in[11];
  const float* b1   = (const float*)d_in[12];
  const float* W2   = (const float*)d_in[13];
  const float* b2   = (const float*)d_in[14];
  const float* ln2g = (const float*)d_in[15];
  const float* ln2b = (const float*)d_in[16];

  char* ws = (char*)d_ws;
  constexpr size_t SZ_W768  = (size_t)768*768*2;
  constexpr size_t SZ_W3072 = (size_t)768*3072*2;
  constexpr size_t SZ_HB    = (size_t)8192*768*2;
  u16* wtq = (u16*)(ws);
  u16* wtk = (u16*)(ws + SZ_W768);
  u16* wtv = (u16*)(ws + 2*SZ_W768);
  u16* wto = (u16*)(ws + 3*SZ_W768);
  u16* wt1 = (u16*)(ws + 4*SZ_W768);
  u16* wt2 = (u16*)(ws + 4*SZ_W768 + SZ_W3072);
  char* p0 = ws + 4*SZ_W768 + 2*SZ_W3072;
  u16*   hbuf = (u16*)p0;               // LN out; later aliased as vtbuf, then LN2 out
  u16*   qbuf = (u16*)(p0 + SZ_HB);
  u16*   kbuf = (u16*)(p0 + 2*SZ_HB);
  u16*   vbuf = (u16*)(p0 + 3*SZ_HB);
  u16*   cbuf = (u16*)(p0 + 4*SZ_HB);
  float* x1   = (float*)(p0 + 5*SZ_HB);
  u16*   vtbuf = hbuf;                  // 24*64*4096*2 == 8192*768*2 bytes exactly
  u16*   ffa  = qbuf;                   // reuse q/k/v region for FF activations
  float* outp = (float*)d_out;

  // weight transpose + f32->bf16
  wconv_kernel<<<dim3(24,24), 256, 0, stream>>>(Wq, wtq, 768, 768);
  wconv_kernel<<<dim3(24,24), 256, 0, stream>>>(Wk, wtk, 768, 768);
  wconv_kernel<<<dim3(24,24), 256, 0, stream>>>(Wv, wtv, 768, 768);
  wconv_kernel<<<dim3(24,24), 256, 0, stream>>>(Wo, wto, 768, 768);
  wconv_kernel<<<dim3(24,96), 256, 0, stream>>>(W1, wt1, 768, 3072);
  wconv_kernel<<<dim3(96,24), 256, 0, stream>>>(W2, wt2, 3072, 768);

  // LN1 -> hbuf
  ln_kernel<<<8192, 256, 0, stream>>>(x, ln1g, ln1b, hbuf);
  // QKV (z-fused); Q pre-scaled by 1/sqrt(HD)=0.125 for softmax
  gemm_kernel<false,false,true><<<dim3(64,6,3), 256, 0, stream>>>(
      hbuf, wtq, (size_t)768*768, bq, bk, bv, nullptr, qbuf, (size_t)8192*768,
      8192, 768, 768, 0.125f);
  // V per-head transpose (perm layout) -> vtbuf (aliases hbuf)
  vconv_kernel<<<dim3(64,24), 256, 0, stream>>>(vbuf, vtbuf);
  // attention
  attn_kernel<<<768, 256, 0, stream>>>(qbuf, kbuf, vtbuf, cbuf);
  // Wo + residual(x) -> x1 (f32)
  gemm_kernel<false,true,false><<<dim3(64,6,1), 256, 0, stream>>>(
      cbuf, wto, 0, bo, bo, bo, x, x1, 0, 8192, 768, 768, 1.0f);
  // LN2 -> hbuf (bf16; overwrites vtbuf, attention is done)
  ln_kernel<<<8192, 256, 0, stream>>>(x1, ln2g, ln2b, hbuf);
  // FF1 + gelu -> ffa (bf16)
  gemm_kernel<true,false,true><<<dim3(64,24,1), 256, 0, stream>>>(
      hbuf, wt1, 0, b1, b1, b1, nullptr, ffa, 0, 8192, 3072, 768, 1.0f);
  // FF2 + residual(x1) -> out (f32)
  gemm_kernel<false,true,false><<<dim3(64,6,1), 256, 0, stream>>>(
      ffa, wt2, 0, b2, b2, b2, x1, outp, 0, 8192, 768, 3072, 1.0f);
}